// Round 9
// baseline (348.199 us; speedup 1.0000x reference)
//
#include <hip/hip_runtime.h>
#include <cstddef>
#include <cstdint>

#define TT 2048
#define HH 16
#define EPSV 1.1920929e-07f
#define QSCALE 0.08838834764831845f   // 1/sqrt(128)
#define LOG2E 1.4426950408889634f
#define THRL 11.0f                    // defer-rescale threshold (log2 units)

typedef short bfv8 __attribute__((ext_vector_type(8)));
typedef short bfv4 __attribute__((ext_vector_type(4)));
typedef float f32x4 __attribute__((ext_vector_type(4)));
typedef unsigned u32x2 __attribute__((ext_vector_type(2)));

__device__ __forceinline__ short f2bf(float f) {
    unsigned u = __builtin_bit_cast(unsigned, f);
    u += 0x7FFFu + ((u >> 16) & 1u);          // RNE
    return (short)(u >> 16);
}
__device__ __forceinline__ float bf2f(short s) {
    unsigned u = ((unsigned)(unsigned short)s) << 16;
    return __builtin_bit_cast(float, u);
}
__device__ __forceinline__ bfv8 pack8(const float4 a, const float4 b) {
    bfv8 r;
    r[0]=f2bf(a.x); r[1]=f2bf(a.y); r[2]=f2bf(a.z); r[3]=f2bf(a.w);
    r[4]=f2bf(b.x); r[5]=f2bf(b.y); r[6]=f2bf(b.z); r[7]=f2bf(b.w);
    return r;
}
__device__ __forceinline__ void gload16(const void* g, void* l) {
    __builtin_amdgcn_global_load_lds(
        (const __attribute__((address_space(1))) unsigned int*)g,
        (__attribute__((address_space(3))) unsigned int*)l, 16, 0, 0);
}
// 2xf32 -> packed bf16 pair (RNE), single instruction  [proven r6]
__device__ __forceinline__ unsigned cvtpk(float a, float b) {
    unsigned r;
    asm("v_cvt_pk_bf16_f32 %0, %1, %2" : "=v"(r) : "v"(a), "v"(b));
    return r;
}
// exp2 via raw v_exp_f32 (s_nop covers trans-op hazard)  [proven r6]
__device__ __forceinline__ float fexp2(float x) {
    float y;
    asm volatile("v_exp_f32 %0, %1\n\ts_nop 1" : "=v"(y) : "v"(x));
    return y;
}
__device__ __forceinline__ float bperm(float v, int addr) {
    return __builtin_bit_cast(float,
        __builtin_amdgcn_ds_bpermute(addr, __builtin_bit_cast(int, v)));
}
__device__ __forceinline__ bfv4 mkfrag(float a, float b, float c, float d) {
    u32x2 t; t[0] = cvtpk(a, b); t[1] = cvtpk(c, d);
    return __builtin_bit_cast(bfv4, t);
}

// ---------------------------------------------------------------------------
__global__ __launch_bounds__(256) void convx(const float* __restrict__ src,
                                             short* __restrict__ dst, int n8)
{
    int i = blockIdx.x * blockDim.x + threadIdx.x;
    int stride = gridDim.x * blockDim.x;
    for (; i < n8; i += stride) {
        float4 a = ((const float4*)src)[2*i], b = ((const float4*)src)[2*i+1];
        ((bfv8*)dst)[i] = pack8(a, b);
    }
}

// ---------------------------------------------------------------------------
// transpose-convert: src f32 [R][C] -> dst bf16 [C][R]. Grid (C/64, R/64).
// ---------------------------------------------------------------------------
__global__ __launch_bounds__(256) void wtrans(const float* __restrict__ src,
                                              short* __restrict__ dst, int R, int C)
{
    __shared__ short tile[64][72];
    const int tid = threadIdx.x;
    const int r0 = blockIdx.y * 64, c0 = blockIdx.x * 64;
    {
        const int i = tid >> 2, c = (tid & 3) * 16;
        const float* sp = src + ((size_t)(r0 + i)) * C + c0 + c;
        float4 v0 = ((const float4*)sp)[0], v1 = ((const float4*)sp)[1];
        float4 v2 = ((const float4*)sp)[2], v3 = ((const float4*)sp)[3];
        *(bfv8*)&tile[i][c]     = pack8(v0, v1);
        *(bfv8*)&tile[i][c + 8] = pack8(v2, v3);
    }
    __syncthreads();
    {
        const int j = tid >> 2, rc = (tid & 3) * 16;
        bfv8 g0, g1;
#pragma unroll
        for (int jj = 0; jj < 8; ++jj) { g0[jj] = tile[rc + jj][j]; g1[jj] = tile[rc + 8 + jj][j]; }
        short* dp = dst + ((size_t)(c0 + j)) * R + r0 + rc;
        *(bfv8*)dp       = g0;
        *(bfv8*)(dp + 8) = g1;
    }
}

// ---------------------------------------------------------------------------
// Deep-pipelined counted-vmcnt GEMM (T3+T4): C = A(MxK) * B^T(NxK), bf16 in.
// Tile 256x128, BK=64, 512 thr (8 waves 4Mx2N, wave 64x64). LDS 96KB dbuf,
// XOR-swizzle via pre-swizzled global source (r5-verified addressing).
// Schedule: prologue stages tiles 0,1; per iter: vmcnt(6) [tile t+1 stays in
// flight through compute] -> barrier -> 2x{ds_read, 16 MFMA} -> barrier ->
// issue tile t+2 into freed buffer. Grid (N/128, M/256), %8 == 0.
// ---------------------------------------------------------------------------
template<int OUT_MODE>
__global__ __launch_bounds__(512) void gemm8(
    const short* __restrict__ A, int lda,
    const short* __restrict__ B, int ldb,
    void* __restrict__ Cptr, int ldc, int K)
{
    __shared__ short Asm[2][256 * 64];
    __shared__ short Bsm[2][128 * 64];

    const int nwg = gridDim.x * gridDim.y;
    int lin = blockIdx.y * gridDim.x + blockIdx.x;
    lin = (lin & 7) * (nwg >> 3) + (lin >> 3);
    const int bx = lin % gridDim.x, by = lin / gridDim.x;

    const int tid = threadIdx.x;
    const int w = tid >> 6, lane = tid & 63;
    const int lr = lane & 15, lg = lane >> 4;
    const int wr = w >> 1, wc = w & 1;
    const size_t bm = (size_t)by * 256, bn = (size_t)bx * 128;

    const int crow = tid >> 3, cunit = tid & 7;
    const short* Ag = A + (bm + crow) * (size_t)lda + (cunit ^ (crow & 7)) * 8;
    const short* Bg = B + (bn + crow) * (size_t)ldb + (cunit ^ (crow & 7)) * 8;
    const int ldsOff = crow * 64 + cunit * 8;

    // stage all 6 chunks (48KB) of K-tile at col kk into buffer bb
    auto stage = [&](int kk, int bb) {
        gload16(Bg + kk,                        &Bsm[bb][ldsOff]);
        gload16(Bg + (size_t)64 * ldb + kk,     &Bsm[bb][4096 + ldsOff]);
        gload16(Ag + kk,                        &Asm[bb][ldsOff]);
        gload16(Ag + (size_t)64 * lda + kk,     &Asm[bb][4096 + ldsOff]);
        gload16(Ag + (size_t)128 * lda + kk,    &Asm[bb][8192 + ldsOff]);
        gload16(Ag + (size_t)192 * lda + kk,    &Asm[bb][12288 + ldsOff]);
    };

    f32x4 acc[4][4] = {};

    const int NT = K >> 6;
    stage(0, 0);
    if (NT > 1) stage(64, 1);

    for (int t = 0; t < NT; ++t) {
        const int c = t & 1;
        if (t + 1 < NT) asm volatile("s_waitcnt vmcnt(6)" ::: "memory");
        else            asm volatile("s_waitcnt vmcnt(0)" ::: "memory");
        __builtin_amdgcn_s_barrier();

#pragma unroll
        for (int ksub = 0; ksub < 2; ++ksub) {
            bfv8 ah[4], bk[4];
#pragma unroll
            for (int j = 0; j < 4; ++j) {
                const int row = wc * 64 + j * 16 + lr;
                bk[j] = *(const bfv8*)&Bsm[c][row * 64 + (((ksub * 4 + lg) ^ (row & 7)) * 8)];
            }
#pragma unroll
            for (int i = 0; i < 4; ++i) {
                const int row = wr * 64 + i * 16 + lr;
                ah[i] = *(const bfv8*)&Asm[c][row * 64 + (((ksub * 4 + lg) ^ (row & 7)) * 8)];
            }
            __builtin_amdgcn_s_setprio(1);
#pragma unroll
            for (int i = 0; i < 4; ++i)
#pragma unroll
                for (int j = 0; j < 4; ++j)
                    acc[i][j] = __builtin_amdgcn_mfma_f32_16x16x32_bf16(ah[i], bk[j], acc[i][j], 0, 0, 0);
            __builtin_amdgcn_s_setprio(0);
        }
        __builtin_amdgcn_s_barrier();
        if (t + 2 < NT) stage((t + 2) << 6, c);
    }

#pragma unroll
    for (int i = 0; i < 4; ++i) {
        const size_t r0 = bm + wr * 64 + i * 16 + 4 * lg;
        const size_t c0 = bn + wc * 64 + lr;
#pragma unroll
        for (int j = 0; j < 4; ++j)
#pragma unroll
            for (int r = 0; r < 4; ++r) {
                const size_t off = (r0 + r) * (size_t)ldc + c0 + j * 16;
                if (OUT_MODE == 0) ((float*)Cptr)[off] = acc[i][j][r];
                else               ((short*)Cptr)[off] = f2bf(acc[i][j][r]);
            }
    }
}

// ---------------------------------------------------------------------------
// k = rmsnorm(k_content + rope(k_pe)); bf16 in, bf16 head-major out [b,h,t,d]
// ---------------------------------------------------------------------------
__global__ __launch_bounds__(256) void finalize_k(
    const short* __restrict__ kc, const short* __restrict__ pe,
    const float* __restrict__ cosb, const float* __restrict__ sinb,
    short* __restrict__ kb)
{
    const int gw = blockIdx.x * 4 + (threadIdx.x >> 6);
    const int l = threadIdx.x & 63;
    const int r = gw >> 4, h = gw & 15;
    const int t = r & (TT - 1), b = r >> 11;
    const size_t kcb = (size_t)r * 4096 + h * 128;
    const size_t peb = (size_t)r * 2048 + h * 128;

    float x1 = bf2f(pe[peb + l]), x2 = bf2f(pe[peb + 64 + l]);
    float c = cosb[t * 64 + l], s = sinb[t * 64 + l];
    float lo = bf2f(kc[kcb + l])      + x1 * c + x2 * s;
    float hi = bf2f(kc[kcb + 64 + l]) - x1 * s + x2 * c;

    float ss = lo * lo + hi * hi;
#pragma unroll
    for (int o = 32; o; o >>= 1) ss += __shfl_xor(ss, o);
    float rr = rsqrtf(ss * (1.0f / 128.0f) + EPSV);
    const size_t ob = (((size_t)b * HH + h) * TT + t) * 128;
    kb[ob + l]      = f2bf(lo * rr);
    kb[ob + 64 + l] = f2bf(hi * rr);
}

// v: KV2 cols 2048..4095 -> vb [b,h,d,t] bf16. Grid (T/64, 2, 32)
__global__ __launch_bounds__(256) void vtrans(
    const short* __restrict__ src, short* __restrict__ dst)
{
    __shared__ short tile[64][72];
    const int tt = blockIdx.x, dt = blockIdx.y, bh = blockIdx.z;
    const int tid = threadIdx.x;
    {
        const int i = tid >> 2, c = (tid & 3) * 16;
        const size_t sb = ((size_t)((bh >> 4) * TT + tt * 64 + i)) * 4096 + 2048 + (bh & 15) * 128 + dt * 64 + c;
        *(bfv8*)&tile[i][c]     = *(const bfv8*)&src[sb];
        *(bfv8*)&tile[i][c + 8] = *(const bfv8*)&src[sb + 8];
    }
    __syncthreads();
    {
        const int j = tid >> 2, rc = (tid & 3) * 16;
        bfv8 g0, g1;
#pragma unroll
        for (int jj = 0; jj < 8; ++jj) { g0[jj] = tile[rc + jj][j]; g1[jj] = tile[rc + 8 + jj][j]; }
        const size_t db = (((size_t)bh) * 128 + dt * 64 + j) * TT + tt * 64 + rc;
        *(bfv8*)&dst[db]     = g0;
        *(bfv8*)&dst[db + 8] = g1;
    }
}

// ---------------------------------------------------------------------------
// attn helpers. Swapped-QK layout: s[ct][r] at lane (lr,lg) = S[key = ct*16 +
// 4*lg + r][q = lr] (q local to wave's 16 rows, key local to 64-tile).
// ---------------------------------------------------------------------------
__device__ __forceinline__ void qk_dual(const short* __restrict__ Ks,
    const bfv8 aq1[4], const bfv8 aq2[4], f32x4 s1[4], f32x4 s2[4], int lr, int lg)
{
    const int swz = lr & 7;
#pragma unroll
    for (int ct = 0; ct < 4; ++ct) {
        f32x4 a1 = {0.f, 0.f, 0.f, 0.f}, a2 = {0.f, 0.f, 0.f, 0.f};
        const int row = ct * 16 + lr;
#pragma unroll
        for (int ks = 0; ks < 4; ++ks) {
            const bfv8 bk = *(const bfv8*)&Ks[row * 128 + (((ks * 4 + lg) ^ swz) * 8)];
            a1 = __builtin_amdgcn_mfma_f32_16x16x32_bf16(bk, aq1[ks], a1, 0, 0, 0);
            a2 = __builtin_amdgcn_mfma_f32_16x16x32_bf16(bk, aq2[ks], a2, 0, 0, 0);
        }
        s1[ct] = a1; s2[ct] = a2;
    }
}

__device__ __forceinline__ void qk_one(const short* __restrict__ Ks,
    const bfv8 aq[4], f32x4 s[4], int lr, int lg)
{
    const int swz = lr & 7;
#pragma unroll
    for (int ct = 0; ct < 4; ++ct) {
        f32x4 a = {0.f, 0.f, 0.f, 0.f};
        const int row = ct * 16 + lr;
#pragma unroll
        for (int ks = 0; ks < 4; ++ks) {
            const bfv8 bk = *(const bfv8*)&Ks[row * 128 + (((ks * 4 + lg) ^ swz) * 8)];
            a = __builtin_amdgcn_mfma_f32_16x16x32_bf16(bk, aq[ks], a, 0, 0, 0);
        }
        s[ct] = a;
    }
}

// diag mask: key local (ct*16+4*lg+r) > q local (w*16+lr)
__device__ __forceinline__ void mask_diag(f32x4 s[4], int lr, int lg, int w)
{
    const int qq = w * 16 + lr;
#pragma unroll
    for (int ct = 0; ct < 4; ++ct)
#pragma unroll
        for (int r = 0; r < 4; ++r)
            if (ct * 16 + 4 * lg + r > qq) s[ct][r] = -__builtin_inff();
}

// per-lane online softmax for q = lr; m,l per-lane scalars (replicated over lg)
__device__ __forceinline__ void softmax_lane(f32x4 s[4], float& m, float& l,
                                             f32x4 o[8], int a0)
{
    float c0 = fmaxf(fmaxf(s[0][0], s[0][1]), fmaxf(s[0][2], s[0][3]));
    float c1 = fmaxf(fmaxf(s[1][0], s[1][1]), fmaxf(s[1][2], s[1][3]));
    float c2 = fmaxf(fmaxf(s[2][0], s[2][1]), fmaxf(s[2][2], s[2][3]));
    float c3 = fmaxf(fmaxf(s[3][0], s[3][1]), fmaxf(s[3][2], s[3][3]));
    float mt = fmaxf(fmaxf(c0, c1), fmaxf(c2, c3));
    mt = fmaxf(mt, __shfl_xor(mt, 16));
    mt = fmaxf(mt, __shfl_xor(mt, 32));
    if (!__all(mt - m <= THRL)) {
        float mn = fmaxf(m, mt);
        float alpha = fexp2(m - mn);
        m = mn;
        l *= alpha;
        // o[dt][j] holds q = 4*lg + j; alpha for that q lives at lane lg*20 + j
        float av0 = bperm(alpha, a0);
        float av1 = bperm(alpha, a0 + 4);
        float av2 = bperm(alpha, a0 + 8);
        float av3 = bperm(alpha, a0 + 12);
#pragma unroll
        for (int dt = 0; dt < 8; ++dt) {
            o[dt][0] *= av0; o[dt][1] *= av1;
            o[dt][2] *= av2; o[dt][3] *= av3;
        }
    }
    f32x4 acc = {0.f, 0.f, 0.f, 0.f};
#pragma unroll
    for (int ct = 0; ct < 4; ++ct) {
#pragma unroll
        for (int r = 0; r < 4; ++r) s[ct][r] = fexp2(s[ct][r] - m);
        acc += s[ct];
    }
    float rs = (acc[0] + acc[1]) + (acc[2] + acc[3]);
    rs += __shfl_xor(rs, 16);
    rs += __shfl_xor(rs, 32);
    l += rs;
}

// P store: lane's 4 keys per ct are consecutive -> one b64 write per ct
__device__ __forceinline__ void p_store(short (&Psw)[16][72], const f32x4 s[4],
                                        int lr, int lg)
{
#pragma unroll
    for (int ct = 0; ct < 4; ++ct)
        *(bfv4*)&Psw[lr][ct * 16 + 4 * lg] = mkfrag(s[ct][0], s[ct][1], s[ct][2], s[ct][3]);
}

// PV via proven 16x16x32: A = P (LDS, A-layout), B = V rows (d). Shares bv.
__device__ __forceinline__ void pv_dual(const short* __restrict__ Vs,
    const short (&P1)[16][72], const short (&P2)[16][72],
    f32x4 o1[8], f32x4 o2[8], int lr, int lg)
{
    const bfv8 pa0 = *(const bfv8*)&P1[lr][lg * 8];
    const bfv8 pa1 = *(const bfv8*)&P1[lr][32 + lg * 8];
    const bfv8 pb0 = *(const bfv8*)&P2[lr][lg * 8];
    const bfv8 pb1 = *(const bfv8*)&P2[lr][32 + lg * 8];
    const int swz = lr & 7;
#pragma unroll
    for (int dt = 0; dt < 8; ++dt) {
        const int row = dt * 16 + lr;
        const bfv8 bv0 = *(const bfv8*)&Vs[row * 64 + ((lg ^ swz) * 8)];
        const bfv8 bv1 = *(const bfv8*)&Vs[row * 64 + (((4 + lg) ^ swz) * 8)];
        o1[dt] = __builtin_amdgcn_mfma_f32_16x16x32_bf16(pa0, bv0, o1[dt], 0, 0, 0);
        o1[dt] = __builtin_amdgcn_mfma_f32_16x16x32_bf16(pa1, bv1, o1[dt], 0, 0, 0);
        o2[dt] = __builtin_amdgcn_mfma_f32_16x16x32_bf16(pb0, bv0, o2[dt], 0, 0, 0);
        o2[dt] = __builtin_amdgcn_mfma_f32_16x16x32_bf16(pb1, bv1, o2[dt], 0, 0, 0);
    }
}

__device__ __forceinline__ void pv_one(const short* __restrict__ Vs,
    const short (&P2)[16][72], f32x4 o[8], int lr, int lg)
{
    const bfv8 pa0 = *(const bfv8*)&P2[lr][lg * 8];
    const bfv8 pa1 = *(const bfv8*)&P2[lr][32 + lg * 8];
    const int swz = lr & 7;
#pragma unroll
    for (int dt = 0; dt < 8; ++dt) {
        const int row = dt * 16 + lr;
        const bfv8 bv0 = *(const bfv8*)&Vs[row * 64 + ((lg ^ swz) * 8)];
        const bfv8 bv1 = *(const bfv8*)&Vs[row * 64 + (((4 + lg) ^ swz) * 8)];
        o[dt] = __builtin_amdgcn_mfma_f32_16x16x32_bf16(pa0, bv0, o[dt], 0, 0, 0);
        o[dt] = __builtin_amdgcn_mfma_f32_16x16x32_bf16(pa1, bv1, o[dt], 0, 0, 0);
    }
}

// ---------------------------------------------------------------------------
// Pair-balanced causal flash attention: swapped-QK softmax (per-lane), proven
// 16x16x32 PV, single-buffer staging, XCD-clustered remap, fused Q-rmsnorm.
// ---------------------------------------------------------------------------
__global__ __launch_bounds__(256) void attn_kernel(
    const short* __restrict__ qg, const short* __restrict__ kg,
    const short* __restrict__ vg, short* __restrict__ y)
{
    __shared__ short Ks[64 * 128];
    __shared__ short Vs[128 * 64];
    __shared__ short Ps1[4][16][72];
    __shared__ short Ps2[4][16][72];

    const int lin = blockIdx.x + 16 * blockIdx.y + 256 * blockIdx.z;
    const int work = (lin & 7) * 64 + (lin >> 3);
    const int pi = work & 15, h = (work >> 4) & 15, b = work >> 8;
    const int qt1 = pi, qt2 = 31 - pi;
    const int tid = threadIdx.x, w = tid >> 6, lane = tid & 63;
    const int lr = lane & 15, lg = lane >> 4;
    const int a0 = lg * 80;   // byte addr of lane lg*20 (q = 4*lg) for bperm

    const size_t tok0 = ((size_t)b * HH + h) * TT;

    bfv8 aq1[4], aq2[4];
    {
        const size_t q1 = ((size_t)b * TT + qt1 * 64 + w * 16 + lr) * 2048 + h * 128;
        const size_t q2 = ((size_t)b * TT + qt2 * 64 + w * 16 + lr) * 2048 + h * 128;
#pragma unroll
        for (int ks = 0; ks < 4; ++ks) {
            aq1[ks] = *(const bfv8*)&qg[q1 + ks * 32 + lg * 8];
            aq2[ks] = *(const bfv8*)&qg[q2 + ks * 32 + lg * 8];
        }
        // fused rmsnorm * (1/sqrt(D)) * log2(e)
#pragma unroll
        for (int st = 0; st < 2; ++st) {
            bfv8* aq = st ? aq2 : aq1;
            float ss = 0.f;
#pragma unroll
            for (int ks = 0; ks < 4; ++ks)
#pragma unroll
                for (int j = 0; j < 8; ++j) { float f = bf2f(aq[ks][j]); ss = fmaf(f, f, ss); }
            ss += __shfl_xor(ss, 16);
            ss += __shfl_xor(ss, 32);
            float rr = rsqrtf(ss * (1.0f / 128.0f) + EPSV) * (QSCALE * LOG2E);
#pragma unroll
            for (int ks = 0; ks < 4; ++ks)
#pragma unroll
                for (int j = 0; j < 4; ++j) {
                    unsigned u = cvtpk(bf2f(aq[ks][2 * j]) * rr, bf2f(aq[ks][2 * j + 1]) * rr);
                    aq[ks][2 * j]     = (short)u;
                    aq[ks][2 * j + 1] = (short)(u >> 16);
                }
        }
    }

    f32x4 o1[8] = {}; f32x4 o2[8] = {};
    float m1 = -__builtin_inff(), m2 = -__builtin_inff();
    float l1 = 0.f, l2 = 0.f;

    const size_t vhead = ((size_t)b * HH + h) * (size_t)128 * TT;
    const int krow = tid >> 4, kub = (tid & 15) ^ (krow & 7);
    const int vrow = tid >> 3, vub = (tid & 7) ^ (vrow & 7);
    const int wof = w * 512;

    for (int kt = 0; kt <= qt2; ++kt) {
        {
            const size_t kbase = (tok0 + kt * 64) * 128;
#pragma unroll
            for (int p = 0; p < 4; ++p) {
                gload16(kg + kbase + (p * 16 + krow) * 128 + kub * 8, Ks + wof + p * 2048);
                gload16(vg + vhead + (size_t)(p * 32 + vrow) * TT + kt * 64 + vub * 8,
                        Vs + wof + p * 2048);
            }
        }
        __syncthreads();

        if (kt <= qt1) {
            f32x4 s1[4], s2[4];
            qk_dual(Ks, aq1, aq2, s1, s2, lr, lg);
            if (kt == qt1) mask_diag(s1, lr, lg, w);
            softmax_lane(s1, m1, l1, o1, a0);
            softmax_lane(s2, m2, l2, o2, a0);
            p_store(Ps1[w], s1, lr, lg);
            p_store(Ps2[w], s2, lr, lg);
            pv_dual(Vs, Ps1[w], Ps2[w], o1, o2, lr, lg);
        } else {
            f32x4 s2[4];
            qk_one(Ks, aq2, s2, lr, lg);
            if (kt == qt2) mask_diag(s2, lr, lg, w);
            softmax_lane(s2, m2, l2, o2, a0);
            p_store(Ps2[w], s2, lr, lg);
            pv_one(Vs, Ps2[w], o2, lr, lg);
        }
        __syncthreads();
    }

    // epilogue: o[dt][r] is q = 4*lg + r; 1/l for that q lives at lane lg*20 + r
    float n1 = 1.0f / l1, n2 = 1.0f / l2;
    float iv1[4], iv2[4];
#pragma unroll
    for (int r = 0; r < 4; ++r) {
        iv1[r] = bperm(n1, a0 + 4 * r);
        iv2[r] = bperm(n2, a0 + 4 * r);
    }
#pragma unroll
    for (int r = 0; r < 4; ++r) {
        const size_t y1 = ((size_t)b * TT + qt1 * 64 + w * 16 + 4 * lg + r) * 2048 + h * 128 + lr;
        const size_t y2 = ((size_t)b * TT + qt2 * 64 + w * 16 + 4 * lg + r) * 2048 + h * 128 + lr;
#pragma unroll
        for (int dt = 0; dt < 8; ++dt) {
            y[y1 + dt * 16] = f2bf(o1[dt][r] * iv1[r]);
            y[y2 + dt * 16] = f2bf(o2[dt][r] * iv2[r]);
        }
    }
}

// ---------------------------------------------------------------------------
extern "C" void kernel_launch(void* const* d_in, const int* in_sizes, int n_in,
                              void* d_out, int out_size, void* d_ws, size_t ws_size,
                              hipStream_t stream)
{
    const float* x      = (const float*)d_in[0];
    const float* cosb   = (const float*)d_in[1];
    const float* sinb   = (const float*)d_in[2];
    const float* wq_a   = (const float*)d_in[3];
    const float* wq_b   = (const float*)d_in[4];
    const float* wkv_a  = (const float*)d_in[5];
    const float* wk_b   = (const float*)d_in[6];
    const float* wkpe_b = (const float*)d_in[7];
    const float* wv_b   = (const float*)d_in[8];
    const float* wo     = (const float*)d_in[9];

    short* wsp = (short*)d_ws;
    short* W1  = wsp;                 // [2048][2048]  [wq_a^T ; wkv_a^T]
    short* W2  = wsp + 4194304;       // [4096][768]   [wk_b^T ; wv_b^T]
    short* W3  = wsp + 7340032;       // [2048][256]   wkpe_b^T
    short* W4  = wsp + 7864320;       // [2048][1024]  wq_b^T
    short* W5  = wsp + 9961472;       // [2048][2048]  wo^T
    short* C1  = wsp + 14155776;      // [4096][2048]  qlat|kvlat; later y
    short* KV2 = wsp + 22544384;      // [4096][4096]  k_content|v
    short* KPE = wsp + 39321600;      // [4096][2048]  k_pe; later qbuf
    short* KB  = wsp + 47710208;      // [b,h,t,d]
    short* VB  = wsp + 56098816;      // [b,h,d,t]
    short* XB  = (short*)d_out;       // x as bf16 (d_out reused as scratch)

    dim3 blk(256);
    dim3 blk8(512);

    convx<<<2048, blk, 0, stream>>>(x, XB, 1048576);
    wtrans<<<dim3(16, 32), blk, 0, stream>>>(wq_a,   W1,                2048, 1024);
    wtrans<<<dim3(16, 32), blk, 0, stream>>>(wkv_a,  W1 + 1024 * 2048,  2048, 1024);
    wtrans<<<dim3(32, 12), blk, 0, stream>>>(wk_b,   W2,                 768, 2048);
    wtrans<<<dim3(32, 12), blk, 0, stream>>>(wv_b,   W2 + 2048 * 768,    768, 2048);
    wtrans<<<dim3(32,  4), blk, 0, stream>>>(wkpe_b, W3,                 256, 2048);
    wtrans<<<dim3(32, 16), blk, 0, stream>>>(wq_b,   W4,                1024, 2048);
    wtrans<<<dim3(32, 32), blk, 0, stream>>>(wo,     W5,                2048, 2048);

    // [qlat|kvlat] = x @ [wq_a|wkv_a]
    gemm8<1><<<dim3(16, 16), blk8, 0, stream>>>(XB, 2048, W1, 2048, C1, 2048, 2048);
    // [k_content|v] = kv_content @ [wk_b|wv_b]
    gemm8<1><<<dim3(32, 16), blk8, 0, stream>>>(C1 + 1280, 2048, W2, 768, KV2, 4096, 768);
    // k_pe = kv_pe @ wkpe_b
    gemm8<1><<<dim3(16, 16), blk8, 0, stream>>>(C1 + 1024, 2048, W3, 256, KPE, 2048, 256);

    finalize_k<<<16384, blk, 0, stream>>>(KV2, KPE, cosb, sinb, KB);
    vtrans<<<dim3(32, 2, 32), blk, 0, stream>>>(KV2, VB);

    // qbuf = qlat @ wq_b  (into KPE slot; attn rmsnorms on the fly)
    gemm8<1><<<dim3(16, 16), blk8, 0, stream>>>(C1, 2048, W4, 1024, KPE, 2048, 1024);

    // attention: y into C1 slot
    attn_kernel<<<dim3(16, 16, 2), blk, 0, stream>>>(KPE, KB, VB, C1);

    // out = y @ wo
    gemm8<0><<<dim3(16, 16), blk8, 0, stream>>>(C1, 2048, W5, 2048, d_out, 2048, 2048);
}

// Round 11
// 315.594 us; speedup vs baseline: 1.1033x; 1.1033x over previous
//
#include <hip/hip_runtime.h>
#include <cstddef>
#include <cstdint>

#define TT 2048
#define HH 16
#define EPSV 1.1920929e-07f
#define QSCALE 0.08838834764831845f   // 1/sqrt(128)
#define LOG2E 1.4426950408889634f
#define THRL 11.0f                    // defer-rescale threshold (log2 units)

typedef short bfv8 __attribute__((ext_vector_type(8)));
typedef short bfv4 __attribute__((ext_vector_type(4)));
typedef float f32x4 __attribute__((ext_vector_type(4)));
typedef unsigned u32x2 __attribute__((ext_vector_type(2)));

__device__ __forceinline__ short f2bf(float f) {
    unsigned u = __builtin_bit_cast(unsigned, f);
    u += 0x7FFFu + ((u >> 16) & 1u);          // RNE
    return (short)(u >> 16);
}
__device__ __forceinline__ float bf2f(short s) {
    unsigned u = ((unsigned)(unsigned short)s) << 16;
    return __builtin_bit_cast(float, u);
}
__device__ __forceinline__ bfv8 pack8(const float4 a, const float4 b) {
    bfv8 r;
    r[0]=f2bf(a.x); r[1]=f2bf(a.y); r[2]=f2bf(a.z); r[3]=f2bf(a.w);
    r[4]=f2bf(b.x); r[5]=f2bf(b.y); r[6]=f2bf(b.z); r[7]=f2bf(b.w);
    return r;
}
__device__ __forceinline__ void gload16(const void* g, void* l) {
    __builtin_amdgcn_global_load_lds(
        (const __attribute__((address_space(1))) unsigned int*)g,
        (__attribute__((address_space(3))) unsigned int*)l, 16, 0, 0);
}
// 2xf32 -> packed bf16 pair (RNE), single instruction  [proven r6]
__device__ __forceinline__ unsigned cvtpk(float a, float b) {
    unsigned r;
    asm("v_cvt_pk_bf16_f32 %0, %1, %2" : "=v"(r) : "v"(a), "v"(b));
    return r;
}
// exp2 via raw v_exp_f32 (s_nop covers trans-op hazard)  [proven r6]
__device__ __forceinline__ float fexp2(float x) {
    float y;
    asm volatile("v_exp_f32 %0, %1\n\ts_nop 1" : "=v"(y) : "v"(x));
    return y;
}
__device__ __forceinline__ float bperm(float v, int addr) {
    return __builtin_bit_cast(float,
        __builtin_amdgcn_ds_bpermute(addr, __builtin_bit_cast(int, v)));
}
__device__ __forceinline__ bfv4 mkfrag(float a, float b, float c, float d) {
    u32x2 t; t[0] = cvtpk(a, b); t[1] = cvtpk(c, d);
    return __builtin_bit_cast(bfv4, t);
}

// ---------------------------------------------------------------------------
// Fused preprocessing: blocks [0, nx) convert x f32->bf16 (1 bfv8/thread,
// nx = numel(x)/8/256 exactly); blocks [nx, ...) transpose-convert the 7
// weight matrices per descriptor table.
// ---------------------------------------------------------------------------
struct TransDesc { const float* src; short* dst; int R, C, b0; };
struct TransArgs { TransDesc t[7]; };

__global__ __launch_bounds__(256) void pre_all(TransArgs ta,
    const float* __restrict__ xsrc, short* __restrict__ xdst, int nx)
{
    __shared__ short tile[64][72];
    int bid = blockIdx.x;
    if (bid < nx) {
        const int i = bid * 256 + threadIdx.x;
        float4 a = ((const float4*)xsrc)[2 * i], b = ((const float4*)xsrc)[2 * i + 1];
        ((bfv8*)xdst)[i] = pack8(a, b);
        return;
    }
    bid -= nx;
    int e = 0;
#pragma unroll
    for (int k = 1; k < 7; ++k) if (bid >= ta.t[k].b0) e = k;
    const TransDesc D = ta.t[e];
    const int loc = bid - D.b0;
    const int cb = D.C >> 6;
    const int by = loc / cb, bx = loc - by * cb;
    const int tid = threadIdx.x;
    const int r0 = by * 64, c0 = bx * 64;
    {
        const int i = tid >> 2, c = (tid & 3) * 16;
        const float* sp = D.src + ((size_t)(r0 + i)) * D.C + c0 + c;
        float4 v0 = ((const float4*)sp)[0], v1 = ((const float4*)sp)[1];
        float4 v2 = ((const float4*)sp)[2], v3 = ((const float4*)sp)[3];
        *(bfv8*)&tile[i][c]     = pack8(v0, v1);
        *(bfv8*)&tile[i][c + 8] = pack8(v2, v3);
    }
    __syncthreads();
    {
        const int j = tid >> 2, rc = (tid & 3) * 16;
        bfv8 g0, g1;
#pragma unroll
        for (int jj = 0; jj < 8; ++jj) { g0[jj] = tile[rc + jj][j]; g1[jj] = tile[rc + 8 + jj][j]; }
        short* dp = D.dst + ((size_t)(c0 + j)) * D.R + r0 + rc;
        *(bfv8*)dp       = g0;
        *(bfv8*)(dp + 8) = g1;
    }
}

// ---------------------------------------------------------------------------
// 2-phase pipelined GEMM: C = A(MxK) * B^T(NxK layout), bf16 in, 128x128 tile,
// BK=32, 4 waves 2x2. OUT_MODE: 0 f32 row-major, 1 bf16 row-major,
// 2 bf16 transposed-to-[b,h,d,t] (V path; b64 stores along t).
// ---------------------------------------------------------------------------
template<int OUT_MODE>
__global__ __launch_bounds__(256) void gemm_bf16(
    const short* __restrict__ A, int lda,
    const short* __restrict__ B, int ldb,
    void* __restrict__ Cptr, int ldc, int K)
{
    __shared__ short As[2][128 * 32];
    __shared__ short Bs[2][128 * 32];
    const int tid = threadIdx.x;
    const int w = tid >> 6, lane = tid & 63;
    const int lr = lane & 15, lg = lane >> 4;
    const int wr = w >> 1, wc = w & 1;
    const size_t bm = (size_t)blockIdx.y * 128, bn = (size_t)blockIdx.x * 128;

    f32x4 acc[4][4] = {};

    const int r0 = tid >> 2, ch = (tid & 3) * 8;
    const short* aB0 = A + (bm + r0) * (size_t)lda + ch;
    const short* aB1 = aB0 + 64 * (size_t)lda;
    const short* bB0 = B + (bn + r0) * (size_t)ldb + ch;
    const short* bB1 = bB0 + 64 * (size_t)ldb;
    const int wof = w * 512;

    gload16(aB0, As[0] + wof);
    gload16(aB1, As[0] + wof + 2048);
    gload16(bB0, Bs[0] + wof);
    gload16(bB1, Bs[0] + wof + 2048);
    __syncthreads();

    int cur = 0;
    for (int k0 = 0; k0 < K; k0 += 32) {
        if (k0 + 32 < K) {
            gload16(aB0 + k0 + 32, As[cur ^ 1] + wof);
            gload16(aB1 + k0 + 32, As[cur ^ 1] + wof + 2048);
            gload16(bB0 + k0 + 32, Bs[cur ^ 1] + wof);
            gload16(bB1 + k0 + 32, Bs[cur ^ 1] + wof + 2048);
        }
        bfv8 af[4], bfr[4];
#pragma unroll
        for (int i = 0; i < 4; ++i) {
            af[i]  = *(const bfv8*)&As[cur][(wr * 64 + i * 16 + lr) * 32 + lg * 8];
            bfr[i] = *(const bfv8*)&Bs[cur][(wc * 64 + i * 16 + lr) * 32 + lg * 8];
        }
#pragma unroll
        for (int i = 0; i < 4; ++i)
#pragma unroll
            for (int j = 0; j < 4; ++j)
                acc[i][j] = __builtin_amdgcn_mfma_f32_16x16x32_bf16(af[i], bfr[j], acc[i][j], 0, 0, 0);
        __syncthreads();
        cur ^= 1;
    }

    if (OUT_MODE == 2) {
        // V path: out[b][h][d][t], b = bm>>11, t = (bm&2047)+wr*64+4*lg+i*16+{0..3}
        short* out = (short*)Cptr;
        const size_t bb = bm >> 11;
        const int tb = (int)(bm & 2047) + wr * 64 + 4 * lg;
        const int colb = (int)bn + wc * 64 + lr;
#pragma unroll
        for (int i = 0; i < 4; ++i)
#pragma unroll
            for (int j = 0; j < 4; ++j) {
                const int c = colb + j * 16;
                const int h = c >> 7, d = c & 127;
                const size_t idx = (((bb * HH + h) * 128 + d) << 11) + tb + i * 16;
                *(bfv4*)&out[idx] = mkfrag(acc[i][j][0], acc[i][j][1], acc[i][j][2], acc[i][j][3]);
            }
    } else {
        const size_t crow = bm + wr * 64 + 4 * lg;
        const size_t ccol = bn + wc * 64 + lr;
#pragma unroll
        for (int i = 0; i < 4; ++i)
#pragma unroll
            for (int j = 0; j < 4; ++j)
#pragma unroll
                for (int r = 0; r < 4; ++r) {
                    size_t off = (crow + i * 16 + r) * (size_t)ldc + ccol + j * 16;
                    if (OUT_MODE == 0) ((float*)Cptr)[off] = acc[i][j][r];
                    else               ((short*)Cptr)[off] = f2bf(acc[i][j][r]);
                }
    }
}

// ---------------------------------------------------------------------------
// k = rmsnorm(k_content + rope(k_pe)); bf16 in (both [4096][2048]),
// bf16 head-major out [b,h,t,d]
// ---------------------------------------------------------------------------
__global__ __launch_bounds__(256) void finalize_k(
    const short* __restrict__ kc, const short* __restrict__ pe,
    const float* __restrict__ cosb, const float* __restrict__ sinb,
    short* __restrict__ kb)
{
    const int gw = blockIdx.x * 4 + (threadIdx.x >> 6);
    const int l = threadIdx.x & 63;
    const int r = gw >> 4, h = gw & 15;
    const int t = r & (TT - 1), b = r >> 11;
    const size_t kcb = (size_t)r * 2048 + h * 128;
    const size_t peb = (size_t)r * 2048 + h * 128;

    float x1 = bf2f(pe[peb + l]), x2 = bf2f(pe[peb + 64 + l]);
    float c = cosb[t * 64 + l], s = sinb[t * 64 + l];
    float lo = bf2f(kc[kcb + l])      + x1 * c + x2 * s;
    float hi = bf2f(kc[kcb + 64 + l]) - x1 * s + x2 * c;

    float ss = lo * lo + hi * hi;
#pragma unroll
    for (int o = 32; o; o >>= 1) ss += __shfl_xor(ss, o);
    float rr = rsqrtf(ss * (1.0f / 128.0f) + EPSV);
    const size_t ob = (((size_t)b * HH + h) * TT + t) * 128;
    kb[ob + l]      = f2bf(lo * rr);
    kb[ob + 64 + l] = f2bf(hi * rr);
}

// ---------------------------------------------------------------------------
// attn helpers. Swapped-QK layout: s[ct][r] at lane (lr,lg) = S[key = ct*16 +
// 4*lg + r][q = lr] (q local to wave's 16 rows, key local to 64-tile).
// ---------------------------------------------------------------------------
__device__ __forceinline__ void qk_dual(const short* __restrict__ Ks,
    const bfv8 aq1[4], const bfv8 aq2[4], f32x4 s1[4], f32x4 s2[4], int lr, int lg)
{
    const int swz = lr & 7;
#pragma unroll
    for (int ct = 0; ct < 4; ++ct) {
        f32x4 a1 = {0.f, 0.f, 0.f, 0.f}, a2 = {0.f, 0.f, 0.f, 0.f};
        const int row = ct * 16 + lr;
#pragma unroll
        for (int ks = 0; ks < 4; ++ks) {
            const bfv8 bk = *(const bfv8*)&Ks[row * 128 + (((ks * 4 + lg) ^ swz) * 8)];
            a1 = __builtin_amdgcn_mfma_f32_16x16x32_bf16(bk, aq1[ks], a1, 0, 0, 0);
            a2 = __builtin_amdgcn_mfma_f32_16x16x32_bf16(bk, aq2[ks], a2, 0, 0, 0);
        }
        s1[ct] = a1; s2[ct] = a2;
    }
}

__device__ __forceinline__ void qk_one(const short* __restrict__ Ks,
    const bfv8 aq[4], f32x4 s[4], int lr, int lg)
{
    const int swz = lr & 7;
#pragma unroll
    for (int ct = 0; ct < 4; ++ct) {
        f32x4 a = {0.f, 0.f, 0.f, 0.f};
        const int row = ct * 16 + lr;
#pragma unroll
        for (int ks = 0; ks < 4; ++ks) {
            const bfv8 bk = *(const bfv8*)&Ks[row * 128 + (((ks * 4 + lg) ^ swz) * 8)];
            a = __builtin_amdgcn_mfma_f32_16x16x32_bf16(bk, aq[ks], a, 0, 0, 0);
        }
        s[ct] = a;
    }
}

// diag mask: key local (ct*16+4*lg+r) > q local (w*16+lr)
__device__ __forceinline__ void mask_diag(f32x4 s[4], int lr, int lg, int w)
{
    const int qq = w * 16 + lr;
#pragma unroll
    for (int ct = 0; ct < 4; ++ct)
#pragma unroll
        for (int r = 0; r < 4; ++r)
            if (ct * 16 + 4 * lg + r > qq) s[ct][r] = -__builtin_inff();
}

// per-lane online softmax for q = lr; m,l per-lane scalars (replicated over lg)
__device__ __forceinline__ void softmax_lane(f32x4 s[4], float& m, float& l,
                                             f32x4 o[8], int a0)
{
    float c0 = fmaxf(fmaxf(s[0][0], s[0][1]), fmaxf(s[0][2], s[0][3]));
    float c1 = fmaxf(fmaxf(s[1][0], s[1][1]), fmaxf(s[1][2], s[1][3]));
    float c2 = fmaxf(fmaxf(s[2][0], s[2][1]), fmaxf(s[2][2], s[2][3]));
    float c3 = fmaxf(fmaxf(s[3][0], s[3][1]), fmaxf(s[3][2], s[3][3]));
    float mt = fmaxf(fmaxf(c0, c1), fmaxf(c2, c3));
    mt = fmaxf(mt, __shfl_xor(mt, 16));
    mt = fmaxf(mt, __shfl_xor(mt, 32));
    if (!__all(mt - m <= THRL)) {
        float mn = fmaxf(m, mt);
        float alpha = fexp2(m - mn);
        m = mn;
        l *= alpha;
        // o[dt][j] holds q = 4*lg + j; alpha for that q lives at lane lg*20 + j
        float av0 = bperm(alpha, a0);
        float av1 = bperm(alpha, a0 + 4);
        float av2 = bperm(alpha, a0 + 8);
        float av3 = bperm(alpha, a0 + 12);
#pragma unroll
        for (int dt = 0; dt < 8; ++dt) {
            o[dt][0] *= av0; o[dt][1] *= av1;
            o[dt][2] *= av2; o[dt][3] *= av3;
        }
    }
    f32x4 acc = {0.f, 0.f, 0.f, 0.f};
#pragma unroll
    for (int ct = 0; ct < 4; ++ct) {
#pragma unroll
        for (int r = 0; r < 4; ++r) s[ct][r] = fexp2(s[ct][r] - m);
        acc += s[ct];
    }
    float rs = (acc[0] + acc[1]) + (acc[2] + acc[3]);
    rs += __shfl_xor(rs, 16);
    rs += __shfl_xor(rs, 32);
    l += rs;
}

// P store: lane's 4 keys per ct are consecutive -> one b64 write per ct
__device__ __forceinline__ void p_store(short (&Psw)[16][72], const f32x4 s[4],
                                        int lr, int lg)
{
#pragma unroll
    for (int ct = 0; ct < 4; ++ct)
        *(bfv4*)&Psw[lr][ct * 16 + 4 * lg] = mkfrag(s[ct][0], s[ct][1], s[ct][2], s[ct][3]);
}

// PV via proven 16x16x32: A = P (LDS, A-layout), B = V rows (d). Shares bv.
__device__ __forceinline__ void pv_dual(const short* __restrict__ Vs,
    const short (&P1)[16][72], const short (&P2)[16][72],
    f32x4 o1[8], f32x4 o2[8], int lr, int lg)
{
    const bfv8 pa0 = *(const bfv8*)&P1[lr][lg * 8];
    const bfv8 pa1 = *(const bfv8*)&P1[lr][32 + lg * 8];
    const bfv8 pb0 = *(const bfv8*)&P2[lr][lg * 8];
    const bfv8 pb1 = *(const bfv8*)&P2[lr][32 + lg * 8];
    const int swz = lr & 7;
#pragma unroll
    for (int dt = 0; dt < 8; ++dt) {
        const int row = dt * 16 + lr;
        const bfv8 bv0 = *(const bfv8*)&Vs[row * 64 + ((lg ^ swz) * 8)];
        const bfv8 bv1 = *(const bfv8*)&Vs[row * 64 + (((4 + lg) ^ swz) * 8)];
        o1[dt] = __builtin_amdgcn_mfma_f32_16x16x32_bf16(pa0, bv0, o1[dt], 0, 0, 0);
        o1[dt] = __builtin_amdgcn_mfma_f32_16x16x32_bf16(pa1, bv1, o1[dt], 0, 0, 0);
        o2[dt] = __builtin_amdgcn_mfma_f32_16x16x32_bf16(pb0, bv0, o2[dt], 0, 0, 0);
        o2[dt] = __builtin_amdgcn_mfma_f32_16x16x32_bf16(pb1, bv1, o2[dt], 0, 0, 0);
    }
}

__device__ __forceinline__ void pv_one(const short* __restrict__ Vs,
    const short (&P2)[16][72], f32x4 o[8], int lr, int lg)
{
    const bfv8 pa0 = *(const bfv8*)&P2[lr][lg * 8];
    const bfv8 pa1 = *(const bfv8*)&P2[lr][32 + lg * 8];
    const int swz = lr & 7;
#pragma unroll
    for (int dt = 0; dt < 8; ++dt) {
        const int row = dt * 16 + lr;
        const bfv8 bv0 = *(const bfv8*)&Vs[row * 64 + ((lg ^ swz) * 8)];
        const bfv8 bv1 = *(const bfv8*)&Vs[row * 64 + (((4 + lg) ^ swz) * 8)];
        o[dt] = __builtin_amdgcn_mfma_f32_16x16x32_bf16(pa0, bv0, o[dt], 0, 0, 0);
        o[dt] = __builtin_amdgcn_mfma_f32_16x16x32_bf16(pa1, bv1, o[dt], 0, 0, 0);
    }
}

// ---------------------------------------------------------------------------
// Pair-balanced causal flash attention: swapped-QK softmax (per-lane), proven
// 16x16x32 PV, single-buffer staging, XCD-clustered remap, fused Q-rmsnorm.
// ---------------------------------------------------------------------------
__global__ __launch_bounds__(256) void attn_kernel(
    const short* __restrict__ qg, const short* __restrict__ kg,
    const short* __restrict__ vg, short* __restrict__ y)
{
    __shared__ short Ks[64 * 128];
    __shared__ short Vs[128 * 64];
    __shared__ short Ps1[4][16][72];
    __shared__ short Ps2[4][16][72];

    const int lin = blockIdx.x + 16 * blockIdx.y + 256 * blockIdx.z;
    const int work = (lin & 7) * 64 + (lin >> 3);
    const int pi = work & 15, h = (work >> 4) & 15, b = work >> 8;
    const int qt1 = pi, qt2 = 31 - pi;
    const int tid = threadIdx.x, w = tid >> 6, lane = tid & 63;
    const int lr = lane & 15, lg = lane >> 4;
    const int a0 = lg * 80;   // byte addr of lane lg*20 (q = 4*lg) for bperm

    const size_t tok0 = ((size_t)b * HH + h) * TT;

    bfv8 aq1[4], aq2[4];
    {
        const size_t q1 = ((size_t)b * TT + qt1 * 64 + w * 16 + lr) * 2048 + h * 128;
        const size_t q2 = ((size_t)b * TT + qt2 * 64 + w * 16 + lr) * 2048 + h * 128;
#pragma unroll
        for (int ks = 0; ks < 4; ++ks) {
            aq1[ks] = *(const bfv8*)&qg[q1 + ks * 32 + lg * 8];
            aq2[ks] = *(const bfv8*)&qg[q2 + ks * 32 + lg * 8];
        }
        // fused rmsnorm * (1/sqrt(D)) * log2(e)
#pragma unroll
        for (int st = 0; st < 2; ++st) {
            bfv8* aq = st ? aq2 : aq1;
            float ss = 0.f;
#pragma unroll
            for (int ks = 0; ks < 4; ++ks)
#pragma unroll
                for (int j = 0; j < 8; ++j) { float f = bf2f(aq[ks][j]); ss = fmaf(f, f, ss); }
            ss += __shfl_xor(ss, 16);
            ss += __shfl_xor(ss, 32);
            float rr = rsqrtf(ss * (1.0f / 128.0f) + EPSV) * (QSCALE * LOG2E);
#pragma unroll
            for (int ks = 0; ks < 4; ++ks)
#pragma unroll
                for (int j = 0; j < 4; ++j) {
                    unsigned u = cvtpk(bf2f(aq[ks][2 * j]) * rr, bf2f(aq[ks][2 * j + 1]) * rr);
                    aq[ks][2 * j]     = (short)u;
                    aq[ks][2 * j + 1] = (short)(u >> 16);
                }
        }
    }

    f32x4 o1[8] = {}; f32x4 o2[8] = {};
    float m1 = -__builtin_inff(), m2 = -__builtin_inff();
    float l1 = 0.f, l2 = 0.f;

    const size_t vhead = ((size_t)b * HH + h) * (size_t)128 * TT;
    const int krow = tid >> 4, kub = (tid & 15) ^ (krow & 7);
    const int vrow = tid >> 3, vub = (tid & 7) ^ (vrow & 7);
    const int wof = w * 512;

    for (int kt = 0; kt <= qt2; ++kt) {
        {
            const size_t kbase = (tok0 + kt * 64) * 128;
#pragma unroll
            for (int p = 0; p < 4; ++p) {
                gload16(kg + kbase + (p * 16 + krow) * 128 + kub * 8, Ks + wof + p * 2048);
                gload16(vg + vhead + (size_t)(p * 32 + vrow) * TT + kt * 64 + vub * 8,
                        Vs + wof + p * 2048);
            }
        }
        __syncthreads();

        if (kt <= qt1) {
            f32x4 s1[4], s2[4];
            qk_dual(Ks, aq1, aq2, s1, s2, lr, lg);
            if (kt == qt1) mask_diag(s1, lr, lg, w);
            softmax_lane(s1, m1, l1, o1, a0);
            softmax_lane(s2, m2, l2, o2, a0);
            p_store(Ps1[w], s1, lr, lg);
            p_store(Ps2[w], s2, lr, lg);
            pv_dual(Vs, Ps1[w], Ps2[w], o1, o2, lr, lg);
        } else {
            f32x4 s2[4];
            qk_one(Ks, aq2, s2, lr, lg);
            if (kt == qt2) mask_diag(s2, lr, lg, w);
            softmax_lane(s2, m2, l2, o2, a0);
            p_store(Ps2[w], s2, lr, lg);
            pv_one(Vs, Ps2[w], o2, lr, lg);
        }
        __syncthreads();
    }

    // epilogue: o[dt][r] is q = 4*lg + r; 1/l for that q lives at lane lg*20 + r
    float n1 = 1.0f / l1, n2 = 1.0f / l2;
    float iv1[4], iv2[4];
#pragma unroll
    for (int r = 0; r < 4; ++r) {
        iv1[r] = bperm(n1, a0 + 4 * r);
        iv2[r] = bperm(n2, a0 + 4 * r);
    }
#pragma unroll
    for (int r = 0; r < 4; ++r) {
        const size_t y1 = ((size_t)b * TT + qt1 * 64 + w * 16 + 4 * lg + r) * 2048 + h * 128 + lr;
        const size_t y2 = ((size_t)b * TT + qt2 * 64 + w * 16 + 4 * lg + r) * 2048 + h * 128 + lr;
#pragma unroll
        for (int dt = 0; dt < 8; ++dt) {
            y[y1 + dt * 16] = f2bf(o1[dt][r] * iv1[r]);
            y[y2 + dt * 16] = f2bf(o2[dt][r] * iv2[r]);
        }
    }
}

// ---------------------------------------------------------------------------
extern "C" void kernel_launch(void* const* d_in, const int* in_sizes, int n_in,
                              void* d_out, int out_size, void* d_ws, size_t ws_size,
                              hipStream_t stream)
{
    const float* x      = (const float*)d_in[0];
    const float* cosb   = (const float*)d_in[1];
    const float* sinb   = (const float*)d_in[2];
    const float* wq_a   = (const float*)d_in[3];
    const float* wq_b   = (const float*)d_in[4];
    const float* wkv_a  = (const float*)d_in[5];
    const float* wk_b   = (const float*)d_in[6];
    const float* wkpe_b = (const float*)d_in[7];
    const float* wv_b   = (const float*)d_in[8];
    const float* wo     = (const float*)d_in[9];

    short* wsp = (short*)d_ws;
    short* W1  = wsp;                 // [2048][2048]  [wq_a^T ; wkv_a^T]
    short* W2  = wsp + 4194304;       // [4096][768]   [wk_b^T ; wv_b^T]
    short* W3  = wsp + 7340032;       // [2048][256]   wkpe_b^T
    short* W4  = wsp + 7864320;       // [2048][1024]  wq_b^T
    short* W5  = wsp + 9961472;       // [2048][2048]  wo^T
    short* C1  = wsp + 14155776;      // [4096][2048]  qlat|kvlat; later y
    short* KC  = wsp + 22544384;      // [4096][2048]  k_content
    short* KPE = wsp + 30932992;      // [4096][2048]  k_pe; later qbuf
    short* KB  = wsp + 39321600;      // [b,h,t,d]
    short* VB  = wsp + 47710208;      // [b,h,d,t]
    short* XB  = (short*)d_out;       // x as bf16 (d_out reused as scratch)

    dim3 blk(256);

    // fused preprocessing: convx 4096 blocks (exactly numel(x)/8/256) +
    // 7 transposes 3456 blocks
    TransArgs ta;
    ta.t[0] = {wq_a,   W1,                2048, 1024,    0};
    ta.t[1] = {wkv_a,  W1 + 1024 * 2048,  2048, 1024,  512};
    ta.t[2] = {wk_b,   W2,                 768, 2048, 1024};
    ta.t[3] = {wv_b,   W2 + 2048 * 768,    768, 2048, 1408};
    ta.t[4] = {wkpe_b, W3,                 256, 2048, 1792};
    ta.t[5] = {wq_b,   W4,                1024, 2048, 1920};
    ta.t[6] = {wo,     W5,                2048, 2048, 2432};
    pre_all<<<4096 + 3456, blk, 0, stream>>>(ta, x, XB, 4096);

    // [qlat|kvlat] = x @ [wq_a|wkv_a]
    gemm_bf16<1><<<dim3(16, 32), blk, 0, stream>>>(XB, 2048, W1, 2048, C1, 2048, 2048);
    // k_content = kv_content @ wk_b
    gemm_bf16<1><<<dim3(16, 32), blk, 0, stream>>>(C1 + 1280, 2048, W2, 768, KC, 2048, 768);
    // v = kv_content @ wv_b, stored directly as [b,h,d,t]
    gemm_bf16<2><<<dim3(16, 32), blk, 0, stream>>>(C1 + 1280, 2048, W2 + 2048 * 768, 768, VB, 0, 768);
    // k_pe = kv_pe @ wkpe_b
    gemm_bf16<1><<<dim3(16, 32), blk, 0, stream>>>(C1 + 1024, 2048, W3, 256, KPE, 2048, 256);

    finalize_k<<<16384, blk, 0, stream>>>(KC, KPE, cosb, sinb, KB);

    // qbuf = qlat @ wq_b  (into KPE slot; attn rmsnorms on the fly)
    gemm_bf16<1><<<dim3(16, 32), blk, 0, stream>>>(C1, 2048, W4, 1024, KPE, 2048, 1024);

    // attention: y into C1 slot
    attn_kernel<<<dim3(16, 16, 2), blk, 0, stream>>>(KPE, KB, VB, C1);

    // out = y @ wo
    gemm_bf16<0><<<dim3(16, 32), blk, 0, stream>>>(C1, 2048, W5, 2048, d_out, 2048, 2048);
}